// Round 1
// baseline (1022.931 us; speedup 1.0000x reference)
//
#include <hip/hip_runtime.h>
#include <math.h>

#define BB 16
#define SS 16
#define VVV 64
#define EE 64
#define HHH 8
#define NLAYER 4
#define DFF_ 2048
#define LL 1024   /* S*V */
#define BL 16384  /* B*L */

// ---------------- embed: concat = [feat@W_raw+b, ov_emb, poi_emb]; zero mask ----------------
__global__ __launch_bounds__(256) void k_embed(
    const float* __restrict__ features, const int* __restrict__ ovtag,
    const int* __restrict__ poiid, const float* __restrict__ W_raw,
    const float* __restrict__ b_raw, const float* __restrict__ ov_tab,
    const float* __restrict__ poi_tab, float* __restrict__ concat,
    float* __restrict__ zm)
{
  int idx = blockIdx.x * 256 + threadIdx.x;       // < BL*80
  int row = idx / 80;
  int c   = idx - row * 80;
  float f0 = features[row * 3 + 0];
  float f1 = features[row * 3 + 1];
  float f2 = features[row * 3 + 2];
  float out;
  if (c < 64) {
    out = b_raw[c] + f0 * W_raw[c] + f1 * W_raw[64 + c] + f2 * W_raw[128 + c];
  } else if (c < 72) {
    int t = ovtag[row]; int j = c - 64;
    out = (t <= 0) ? 0.f : ov_tab[t * 8 + j];     // padding_idx=0 -> zeros
  } else {
    int t = poiid[row]; int j = c - 72;
    out = (t <= 0) ? 0.f : poi_tab[t * 8 + j];    // padding_idx=0 -> zeros
  }
  concat[idx] = out;
  if (c == 0) zm[row] = ((f0 + f1 + f2) == 0.f) ? 1.f : 0.f;
}

// ---------------- generic fp32 GEMM: C[M,N] = A[M,K]@Bw[K,N] + bias (+pos/type) ----------------
template <int K>
__global__ __launch_bounds__(256) void k_gemm(
    const float* __restrict__ A, const float* __restrict__ Bw,
    const float* __restrict__ bias, float* __restrict__ C,
    int N, int addpos,
    const float* __restrict__ pos_tab, const float* __restrict__ type_tab)
{
  __shared__ float As[64 * 84];   // pad stride 84 (16B-aligned, conflict-light)
  __shared__ float Bs[80 * 64];
  int tid = threadIdx.x;
  int m0 = blockIdx.x * 64;
  int n0 = blockIdx.y * 64;
  for (int p = tid; p < 64 * K; p += 256) {
    int r = p / K, k = p - r * K;
    As[r * 84 + k] = A[(size_t)(m0 + r) * K + k];
  }
  for (int p = tid; p < K * 64; p += 256) {
    int k = p >> 6, c = p & 63;
    Bs[k * 64 + c] = Bw[(size_t)k * N + n0 + c];
  }
  __syncthreads();
  int tr4 = (tid >> 4) << 2, tc4 = (tid & 15) << 2;
  float acc[4][4] = {};
  for (int k = 0; k < K; k += 4) {
    float a_[4][4], b_[4][4];
#pragma unroll
    for (int i = 0; i < 4; i++)
      *(float4*)&a_[i][0] = *(const float4*)&As[(tr4 + i) * 84 + k];
#pragma unroll
    for (int kk = 0; kk < 4; kk++)
      *(float4*)&b_[kk][0] = *(const float4*)&Bs[(k + kk) * 64 + tc4];
#pragma unroll
    for (int kk = 0; kk < 4; kk++)
#pragma unroll
      for (int i = 0; i < 4; i++)
#pragma unroll
        for (int j = 0; j < 4; j++)
          acc[i][j] += a_[i][kk] * b_[kk][j];
  }
#pragma unroll
  for (int i = 0; i < 4; i++) {
    int row = m0 + tr4 + i;
#pragma unroll
    for (int j = 0; j < 4; j++) {
      int col = n0 + tc4 + j;
      float v = acc[i][j] + bias[col];
      if (addpos) {
        int l = row & (LL - 1);
        v += pos_tab[(l >> 6) * 64 + col] + type_tab[(l & 63) * 64 + col];
      }
      C[(size_t)row * N + col] = v;
    }
  }
}

// ---------------- attention: block = (b, h, 256 q-rows); masked online softmax ----------------
__global__ __launch_bounds__(256) void k_attn(
    const float* __restrict__ qkv, const float* __restrict__ zm,
    float* __restrict__ obuf)
{
  __shared__ float KsT[8 * 1024];   // [d][k]
  __shared__ float VsT[8 * 1024];   // exactly 64 KiB total
  int blk = blockIdx.x;
  int qb = blk & 3, h = (blk >> 2) & 7, b = blk >> 5;
  const float* base = qkv + (size_t)b * LL * 192;
  for (int p = threadIdx.x; p < 8192; p += 256) {
    int k = p >> 3, d = p & 7;
    KsT[d * 1024 + k] = base[(size_t)k * 192 + 64 + h * 8 + d];
    VsT[d * 1024 + k] = base[(size_t)k * 192 + 128 + h * 8 + d];
  }
  __syncthreads();
  int qrow = qb * 256 + threadIdx.x;
  int tq = qrow >> 6, vq = qrow & 63;
  const float* zmb = zm + b * LL;
  float q[8];
#pragma unroll
  for (int d = 0; d < 8; d++) q[d] = base[(size_t)qrow * 192 + h * 8 + d];
  const float scale = 0.3535533905932738f;  // 1/sqrt(8)
  float m = -INFINITY, lsum = 0.f;
  float acc[8] = {0.f, 0.f, 0.f, 0.f, 0.f, 0.f, 0.f, 0.f};
  bool zmq = (zmb[qrow] != 0.f);

  auto attend = [&](int k) {
    if (zmb[k] != 0.f) return;
    float s = 0.f;
#pragma unroll
    for (int d = 0; d < 8; d++) s += q[d] * KsT[d * 1024 + k];
    s *= scale;
    if (s <= m) {
      float p = __expf(s - m);
      lsum += p;
#pragma unroll
      for (int d = 0; d < 8; d++) acc[d] += p * VsT[d * 1024 + k];
    } else {
      float r = __expf(m - s);
      lsum = lsum * r + 1.f;
#pragma unroll
      for (int d = 0; d < 8; d++) acc[d] = acc[d] * r + VsT[d * 1024 + k];
      m = s;
    }
  };

  if (!zmq) {
    // allowed iff t_q==t_k OR v_q==v_k: 64 same-t keys + 15 same-v keys
    for (int vv = 0; vv < 64; vv++) attend(tq * 64 + vv);
    for (int tt = 0; tt < 16; tt++) {
      if (tt == tq) continue;
      attend(tt * 64 + vq);
    }
  }
  float inv = 1.f / lsum;
  float* orow = obuf + (size_t)(b * LL + qrow) * 64 + h * 8;
#pragma unroll
  for (int d = 0; d < 8; d++) orow[d] = acc[d] * inv;
}

// ---------------- residual + LayerNorm (wave per row), in-place on x ----------------
__global__ __launch_bounds__(256) void k_resln(
    float* __restrict__ x, const float* __restrict__ tmp, int nparts,
    const float* __restrict__ sc, const float* __restrict__ bs)
{
  int lane = threadIdx.x & 63;
  int row = blockIdx.x * 4 + (threadIdx.x >> 6);
  size_t off = (size_t)row * 64 + lane;
  float val = x[off];
  for (int p = 0; p < nparts; p++) val += tmp[(size_t)p * ((size_t)BL * 64) + off];
  float sum = val;
#pragma unroll
  for (int o = 32; o > 0; o >>= 1) sum += __shfl_xor(sum, o);
  float mean = sum * (1.f / 64.f);
  float d = val - mean;
  float sq = d * d;
#pragma unroll
  for (int o = 32; o > 0; o >>= 1) sq += __shfl_xor(sq, o);
  float var = sq * (1.f / 64.f);
  x[off] = d * rsqrtf(var + 1e-5f) * sc[lane] + bs[lane];
}

// ---------------- fused FFN: out_part[split] = relu(x@W1[:,range])@W2[range,:] ----------------
__global__ __launch_bounds__(256) void k_ffn(
    const float* __restrict__ x, const float* __restrict__ W1,
    const float* __restrict__ b1, const float* __restrict__ W2,
    const float* __restrict__ b2, float* __restrict__ out)
{
  __shared__ float xs[64 * 68];
  __shared__ float ws_[64 * 68];   // reused: W1 chunk then W2 chunk
  __shared__ float hs[64 * 68];
  int tid = threadIdx.x;
  int r0 = blockIdx.x * 64;
  int split = blockIdx.y;          // 0..3, each handles 8 chunks of 64 hidden
  int tr4 = (tid >> 4) << 2, tc4 = (tid & 15) << 2;
  for (int p = tid; p < 4096; p += 256) {
    int r = p >> 6, c = p & 63;
    xs[r * 68 + c] = x[(size_t)(r0 + r) * 64 + c];
  }
  float acc[4][4] = {};
  for (int hc = split * 8; hc < split * 8 + 8; hc++) {
    __syncthreads();  // prior accumulate done reading ws_/hs; xs ready (iter 0)
    for (int p = tid; p < 4096; p += 256) {
      int k = p >> 6, c = p & 63;
      ws_[k * 68 + c] = W1[(size_t)k * DFF_ + hc * 64 + c];
    }
    __syncthreads();
    float hacc[4][4];
#pragma unroll
    for (int i = 0; i < 4; i++)
#pragma unroll
      for (int j = 0; j < 4; j++)
        hacc[i][j] = b1[hc * 64 + tc4 + j];
    for (int k = 0; k < 64; k += 4) {
      float a_[4][4], b_[4][4];
#pragma unroll
      for (int i = 0; i < 4; i++)
        *(float4*)&a_[i][0] = *(const float4*)&xs[(tr4 + i) * 68 + k];
#pragma unroll
      for (int kk = 0; kk < 4; kk++)
        *(float4*)&b_[kk][0] = *(const float4*)&ws_[(k + kk) * 68 + tc4];
#pragma unroll
      for (int kk = 0; kk < 4; kk++)
#pragma unroll
        for (int i = 0; i < 4; i++)
#pragma unroll
          for (int j = 0; j < 4; j++)
            hacc[i][j] += a_[i][kk] * b_[kk][j];
    }
    __syncthreads();  // everyone done reading ws_ (W1)
#pragma unroll
    for (int i = 0; i < 4; i++)
#pragma unroll
      for (int j = 0; j < 4; j++)
        hs[(tr4 + i) * 68 + tc4 + j] = fmaxf(hacc[i][j], 0.f);
    for (int p = tid; p < 4096; p += 256) {
      int k = p >> 6, c = p & 63;
      ws_[k * 68 + c] = W2[(size_t)(hc * 64 + k) * 64 + c];
    }
    __syncthreads();  // hs + W2 chunk visible
    for (int k = 0; k < 64; k += 4) {
      float a_[4][4], b_[4][4];
#pragma unroll
      for (int i = 0; i < 4; i++)
        *(float4*)&a_[i][0] = *(const float4*)&hs[(tr4 + i) * 68 + k];
#pragma unroll
      for (int kk = 0; kk < 4; kk++)
        *(float4*)&b_[kk][0] = *(const float4*)&ws_[(k + kk) * 68 + tc4];
#pragma unroll
      for (int kk = 0; kk < 4; kk++)
#pragma unroll
        for (int i = 0; i < 4; i++)
#pragma unroll
          for (int j = 0; j < 4; j++)
            acc[i][j] += a_[i][kk] * b_[kk][j];
    }
  }
#pragma unroll
  for (int i = 0; i < 4; i++) {
    int row = r0 + tr4 + i;
#pragma unroll
    for (int j = 0; j < 4; j++) {
      int col = tc4 + j;
      float v = acc[i][j];
      if (split == 0) v += b2[col];  // bias added once; parts summed in k_resln
      out[(size_t)split * ((size_t)BL * 64) + (size_t)row * 64 + col] = v;
    }
  }
}

// ---------------- head: out[B,V,3] = x[:, -1] @ W_head + b_head ----------------
__global__ __launch_bounds__(256) void k_head(
    const float* __restrict__ x, const float* __restrict__ Wh,
    const float* __restrict__ bh, float* __restrict__ out)
{
  int id = blockIdx.x * 256 + threadIdx.x;  // < B*V = 1024
  int b = id >> 6, v = id & 63;
  const float* xr = x + (size_t)(b * LL + (SS - 1) * VVV + v) * 64;
  float a0 = bh[0], a1 = bh[1], a2 = bh[2];
  for (int e = 0; e < 64; e++) {
    float xv = xr[e];
    a0 += xv * Wh[e * 3 + 0];
    a1 += xv * Wh[e * 3 + 1];
    a2 += xv * Wh[e * 3 + 2];
  }
  out[id * 3 + 0] = a0;
  out[id * 3 + 1] = a1;
  out[id * 3 + 2] = a2;
}

extern "C" void kernel_launch(void* const* d_in, const int* in_sizes, int n_in,
                              void* d_out, int out_size, void* d_ws, size_t ws_size,
                              hipStream_t stream) {
  const float* features = (const float*)d_in[0];
  const int*   ovtag    = (const int*)d_in[1];
  const int*   poiid    = (const int*)d_in[2];
  const float* W_raw    = (const float*)d_in[3];
  const float* b_raw    = (const float*)d_in[4];
  const float* pos_tab  = (const float*)d_in[5];
  const float* type_tab = (const float*)d_in[6];
  const float* poi_tab  = (const float*)d_in[7];
  const float* ov_tab   = (const float*)d_in[8];
  const float* W_comb   = (const float*)d_in[9];
  const float* b_comb   = (const float*)d_in[10];
  const float* Wqkv     = (const float*)d_in[11];
  const float* bqkv     = (const float*)d_in[12];
  const float* Wo       = (const float*)d_in[13];
  const float* bo       = (const float*)d_in[14];
  const float* ln1_s    = (const float*)d_in[15];
  const float* ln1_b    = (const float*)d_in[16];
  const float* W1       = (const float*)d_in[17];
  const float* b1       = (const float*)d_in[18];
  const float* W2       = (const float*)d_in[19];
  const float* b2       = (const float*)d_in[20];
  const float* ln2_s    = (const float*)d_in[21];
  const float* ln2_b    = (const float*)d_in[22];
  const float* W_head   = (const float*)d_in[23];
  const float* b_head   = (const float*)d_in[24];
  float* out = (float*)d_out;
  float* ws  = (float*)d_ws;

  float* zm     = ws;                         // BL
  float* concat = zm + BL;                    // BL*80
  float* x      = concat + (size_t)BL * 80;   // BL*64
  float* qkvb   = x + (size_t)BL * 64;        // BL*192
  float* obuf   = qkvb + (size_t)BL * 192;    // BL*64
  float* tmp    = obuf + (size_t)BL * 64;     // 4 * BL*64

  k_embed<<<(BL * 80) / 256, 256, 0, stream>>>(features, ovtag, poiid, W_raw,
                                               b_raw, ov_tab, poi_tab, concat, zm);
  k_gemm<80><<<dim3(BL / 64, 1), 256, 0, stream>>>(concat, W_comb, b_comb, x,
                                                   64, 1, pos_tab, type_tab);
  for (int l = 0; l < NLAYER; l++) {
    k_gemm<64><<<dim3(BL / 64, 3), 256, 0, stream>>>(
        x, Wqkv + (size_t)l * EE * 3 * EE, bqkv + l * 3 * EE, qkvb, 192, 0,
        nullptr, nullptr);
    k_attn<<<512, 256, 0, stream>>>(qkvb, zm, obuf);
    k_gemm<64><<<dim3(BL / 64, 1), 256, 0, stream>>>(
        obuf, Wo + (size_t)l * EE * EE, bo + l * EE, tmp, 64, 0, nullptr, nullptr);
    k_resln<<<BL / 4, 256, 0, stream>>>(x, tmp, 1, ln1_s + l * EE, ln1_b + l * EE);
    k_ffn<<<dim3(BL / 64, 4), 256, 0, stream>>>(
        x, W1 + (size_t)l * EE * DFF_, b1 + l * DFF_,
        W2 + (size_t)l * DFF_ * EE, b2 + l * EE, tmp);
    k_resln<<<BL / 4, 256, 0, stream>>>(x, tmp, 4, ln2_s + l * EE, ln2_b + l * EE);
  }
  k_head<<<4, 256, 0, stream>>>(x, W_head, b_head, out);
}

// Round 2
// 697.231 us; speedup vs baseline: 1.4671x; 1.4671x over previous
//
#include <hip/hip_runtime.h>
#include <math.h>

#define BB 16
#define SS 16
#define VVV 64
#define EE 64
#define HHH 8
#define NLAYER 4
#define DFF_ 2048
#define LL 1024   /* S*V */
#define BL 16384  /* B*L */
#define PERL 131072  /* 64*2048 elements per layer of W1 (and W2) */

typedef __attribute__((ext_vector_type(8))) short short8;
typedef __attribute__((ext_vector_type(4))) float f32x4;
typedef __attribute__((ext_vector_type(4))) unsigned short us4;
typedef unsigned short ushortT;

__device__ __forceinline__ ushortT bf16_rn(float x) {
  union { float f; unsigned u; } v; v.f = x;
  unsigned u = v.u + 0x7FFFu + ((v.u >> 16) & 1u);
  return (ushortT)(u >> 16);
}
__device__ __forceinline__ float bf16f(ushortT h) {
  union { unsigned u; float f; } v; v.u = ((unsigned)h) << 16;
  return v.f;
}
// XOR-swizzled index into a [64][64] ushort LDS tile: 16B-aligned rows, <=2-way banks
#define SW(m, k) (((m) << 6) + ((((k) >> 3) ^ ((m) & 7)) << 3) + ((k) & 7))

// ---------------- embed: concat = [feat@W_raw+b, ov_emb, poi_emb]; zero mask ----------------
__global__ __launch_bounds__(256) void k_embed(
    const float* __restrict__ features, const int* __restrict__ ovtag,
    const int* __restrict__ poiid, const float* __restrict__ W_raw,
    const float* __restrict__ b_raw, const float* __restrict__ ov_tab,
    const float* __restrict__ poi_tab, float* __restrict__ concat,
    float* __restrict__ zm)
{
  int idx = blockIdx.x * 256 + threadIdx.x;       // < BL*80
  int row = idx / 80;
  int c   = idx - row * 80;
  float f0 = features[row * 3 + 0];
  float f1 = features[row * 3 + 1];
  float f2 = features[row * 3 + 2];
  float out;
  if (c < 64) {
    out = b_raw[c] + f0 * W_raw[c] + f1 * W_raw[64 + c] + f2 * W_raw[128 + c];
  } else if (c < 72) {
    int t = ovtag[row]; int j = c - 64;
    out = (t <= 0) ? 0.f : ov_tab[t * 8 + j];     // padding_idx=0 -> zeros
  } else {
    int t = poiid[row]; int j = c - 72;
    out = (t <= 0) ? 0.f : poi_tab[t * 8 + j];    // padding_idx=0 -> zeros
  }
  concat[idx] = out;
  if (c == 0) zm[row] = ((f0 + f1 + f2) == 0.f) ? 1.f : 0.f;
}

// ---------------- generic fp32 GEMM: C[M,N] = A[M,K]@Bw[K,N] + bias (+pos/type) ----------------
template <int K>
__global__ __launch_bounds__(256) void k_gemm(
    const float* __restrict__ A, const float* __restrict__ Bw,
    const float* __restrict__ bias, float* __restrict__ C,
    int N, int addpos,
    const float* __restrict__ pos_tab, const float* __restrict__ type_tab)
{
  __shared__ float As[64 * 84];
  __shared__ float Bs[80 * 64];
  int tid = threadIdx.x;
  int m0 = blockIdx.x * 64;
  int n0 = blockIdx.y * 64;
  for (int p = tid; p < 64 * K; p += 256) {
    int r = p / K, k = p - r * K;
    As[r * 84 + k] = A[(size_t)(m0 + r) * K + k];
  }
  for (int p = tid; p < K * 64; p += 256) {
    int k = p >> 6, c = p & 63;
    Bs[k * 64 + c] = Bw[(size_t)k * N + n0 + c];
  }
  __syncthreads();
  int tr4 = (tid >> 4) << 2, tc4 = (tid & 15) << 2;
  float acc[4][4] = {};
  for (int k = 0; k < K; k += 4) {
    float a_[4][4], b_[4][4];
#pragma unroll
    for (int i = 0; i < 4; i++)
      *(float4*)&a_[i][0] = *(const float4*)&As[(tr4 + i) * 84 + k];
#pragma unroll
    for (int kk = 0; kk < 4; kk++)
      *(float4*)&b_[kk][0] = *(const float4*)&Bs[(k + kk) * 64 + tc4];
#pragma unroll
    for (int kk = 0; kk < 4; kk++)
#pragma unroll
      for (int i = 0; i < 4; i++)
#pragma unroll
        for (int j = 0; j < 4; j++)
          acc[i][j] += a_[i][kk] * b_[kk][j];
  }
#pragma unroll
  for (int i = 0; i < 4; i++) {
    int row = m0 + tr4 + i;
#pragma unroll
    for (int j = 0; j < 4; j++) {
      int col = n0 + tc4 + j;
      float v = acc[i][j] + bias[col];
      if (addpos) {
        int l = row & (LL - 1);
        v += pos_tab[(l >> 6) * 64 + col] + type_tab[(l & 63) * 64 + col];
      }
      C[(size_t)row * N + col] = v;
    }
  }
}

// ---------------- attention: block = (b, h, 256 q-rows); masked online softmax ----------------
__global__ __launch_bounds__(256) void k_attn(
    const float* __restrict__ qkv, const float* __restrict__ zm,
    float* __restrict__ obuf)
{
  __shared__ float KsT[8 * 1024];
  __shared__ float VsT[8 * 1024];
  int blk = blockIdx.x;
  int qb = blk & 3, h = (blk >> 2) & 7, b = blk >> 5;
  const float* base = qkv + (size_t)b * LL * 192;
  for (int p = threadIdx.x; p < 8192; p += 256) {
    int k = p >> 3, d = p & 7;
    KsT[d * 1024 + k] = base[(size_t)k * 192 + 64 + h * 8 + d];
    VsT[d * 1024 + k] = base[(size_t)k * 192 + 128 + h * 8 + d];
  }
  __syncthreads();
  int qrow = qb * 256 + threadIdx.x;
  int tq = qrow >> 6, vq = qrow & 63;
  const float* zmb = zm + b * LL;
  float q[8];
#pragma unroll
  for (int d = 0; d < 8; d++) q[d] = base[(size_t)qrow * 192 + h * 8 + d];
  const float scale = 0.3535533905932738f;
  float m = -INFINITY, lsum = 0.f;
  float acc[8] = {0.f, 0.f, 0.f, 0.f, 0.f, 0.f, 0.f, 0.f};
  bool zmq = (zmb[qrow] != 0.f);

  auto attend = [&](int k) {
    if (zmb[k] != 0.f) return;
    float s = 0.f;
#pragma unroll
    for (int d = 0; d < 8; d++) s += q[d] * KsT[d * 1024 + k];
    s *= scale;
    if (s <= m) {
      float p = __expf(s - m);
      lsum += p;
#pragma unroll
      for (int d = 0; d < 8; d++) acc[d] += p * VsT[d * 1024 + k];
    } else {
      float r = __expf(m - s);
      lsum = lsum * r + 1.f;
#pragma unroll
      for (int d = 0; d < 8; d++) acc[d] = acc[d] * r + VsT[d * 1024 + k];
      m = s;
    }
  };

  if (!zmq) {
    for (int vv = 0; vv < 64; vv++) attend(tq * 64 + vv);
    for (int tt = 0; tt < 16; tt++) {
      if (tt == tq) continue;
      attend(tt * 64 + vq);
    }
  }
  float inv = 1.f / lsum;
  float* orow = obuf + (size_t)(b * LL + qrow) * 64 + h * 8;
#pragma unroll
  for (int d = 0; d < 8; d++) orow[d] = acc[d] * inv;
}

// ---------------- residual + LayerNorm (wave per row), in-place on x ----------------
__global__ __launch_bounds__(256) void k_resln(
    float* __restrict__ x, const float* __restrict__ tmp, int nparts,
    const float* __restrict__ sc, const float* __restrict__ bs)
{
  int lane = threadIdx.x & 63;
  int row = blockIdx.x * 4 + (threadIdx.x >> 6);
  size_t off = (size_t)row * 64 + lane;
  float val = x[off];
  for (int p = 0; p < nparts; p++) val += tmp[(size_t)p * ((size_t)BL * 64) + off];
  float sum = val;
#pragma unroll
  for (int o = 32; o > 0; o >>= 1) sum += __shfl_xor(sum, o);
  float mean = sum * (1.f / 64.f);
  float d = val - mean;
  float sq = d * d;
#pragma unroll
  for (int o = 32; o > 0; o >>= 1) sq += __shfl_xor(sq, o);
  float var = sq * (1.f / 64.f);
  x[off] = d * rsqrtf(var + 1e-5f) * sc[lane] + bs[lane];
}

// ---------------- prep: transposed bf16 hi/lo copies of W1,W2 (K-contiguous) ----------------
// w1t[l][n][k] = W1[l][k][n]  (n in [0,2048), k in [0,64))
// w2t[l][n][k] = W2[l][k][n]  (n in [0,64),   k in [0,2048))
__global__ __launch_bounds__(256) void k_prep(
    const float* __restrict__ W1, const float* __restrict__ W2,
    ushortT* __restrict__ w1t_hi, ushortT* __restrict__ w1t_lo,
    ushortT* __restrict__ w2t_hi, ushortT* __restrict__ w2t_lo)
{
  int idx = blockIdx.x * 256 + threadIdx.x;  // < 2*NL*PERL = 1048576
  float v;
  if (idx < NLAYER * PERL) {
    int l = idx >> 17, r = idx & (PERL - 1);
    int n = r >> 6, k = r & 63;
    v = W1[(size_t)l * PERL + k * 2048 + n];
    ushortT hi = bf16_rn(v);
    w1t_hi[idx] = hi;
    w1t_lo[idx] = bf16_rn(v - bf16f(hi));
  } else {
    int j = idx - NLAYER * PERL;
    int l = j >> 17, r = j & (PERL - 1);
    int n = r >> 11, k = r & 2047;
    v = W2[(size_t)l * PERL + k * 64 + n];
    ushortT hi = bf16_rn(v);
    w2t_hi[j] = hi;
    w2t_lo[j] = bf16_rn(v - bf16f(hi));
  }
}

// ---------------- FFN via bf16x3 MFMA: out_part[split] = relu(x@W1[:,rng])@W2[rng,:] ----------
__global__ __launch_bounds__(256) void k_ffn(
    const float* __restrict__ x,
    const ushortT* __restrict__ w1t_hi, const ushortT* __restrict__ w1t_lo,
    const ushortT* __restrict__ w2t_hi, const ushortT* __restrict__ w2t_lo,
    const float* __restrict__ b1, const float* __restrict__ b2,
    float* __restrict__ out)
{
  __shared__ ushortT xsh[4096], xsl[4096];
  __shared__ ushortT wsh[4096], wsl[4096];   // reused: W1 chunk then W2 chunk
  __shared__ ushortT hsh[4096], hsl[4096];
  int tid = threadIdx.x;
  int r0 = blockIdx.x * 64;
  int split = blockIdx.y;                    // 0..3, chunks [split*8, split*8+8)
  int wave = tid >> 6, lane = tid & 63;
  int quad = lane >> 4, l15 = lane & 15;
  int wm = wave >> 1, wn = wave & 1;         // 2x2 wave grid: M 32, N 32 each

  // stage + convert x tile (64x64 contiguous)
  const float* xtile = x + (size_t)r0 * 64;
  for (int p = tid; p < 4096; p += 256) {
    int m = p >> 6, k = p & 63;
    float v = xtile[p];
    ushortT hi = bf16_rn(v);
    int id = SW(m, k);
    xsh[id] = hi;
    xsl[id] = bf16_rn(v - bf16f(hi));
  }
  __syncthreads();

  // hoist x A-fragments: [mt][ks]
  short8 xa_h[2][2], xa_l[2][2];
#pragma unroll
  for (int mt = 0; mt < 2; mt++)
#pragma unroll
    for (int ks = 0; ks < 2; ks++) {
      int m = wm * 32 + mt * 16 + l15;
      int k0 = ks * 32 + quad * 8;
      xa_h[mt][ks] = *(const short8*)&xsh[SW(m, k0)];
      xa_l[mt][ks] = *(const short8*)&xsl[SW(m, k0)];
    }

  f32x4 acc[2][2];
#pragma unroll
  for (int mt = 0; mt < 2; mt++)
#pragma unroll
    for (int nt = 0; nt < 2; nt++) {
      float bv = (split == 0) ? b2[wn * 32 + nt * 16 + l15] : 0.f;
      acc[mt][nt] = (f32x4){bv, bv, bv, bv};
    }

  for (int i = 0; i < 8; i++) {
    int hcg = split * 8 + i;
    __syncthreads();  // prev GEMM2 done reading wsh/wsl + hs
    // stage W1 chunk: contiguous 4096 ushorts each
    {
      const ushortT* g1h = w1t_hi + (size_t)hcg * 4096;
      const ushortT* g1l = w1t_lo + (size_t)hcg * 4096;
      for (int p = tid; p < 1024; p += 256) {
        int n = p >> 4, s = p & 15;
        int id = SW(n, s * 4);
        *(us4*)&wsh[id] = *(const us4*)&g1h[p * 4];
        *(us4*)&wsl[id] = *(const us4*)&g1l[p * 4];
      }
    }
    __syncthreads();
    // GEMM1: H = x @ W1chunk + b1
    f32x4 hacc[2][2];
#pragma unroll
    for (int nt = 0; nt < 2; nt++) {
      float bv = b1[hcg * 64 + wn * 32 + nt * 16 + l15];
      hacc[0][nt] = (f32x4){bv, bv, bv, bv};
      hacc[1][nt] = (f32x4){bv, bv, bv, bv};
    }
#pragma unroll
    for (int ks = 0; ks < 2; ks++) {
      short8 bh[2], bl[2];
#pragma unroll
      for (int nt = 0; nt < 2; nt++) {
        int n = wn * 32 + nt * 16 + l15;
        int k0 = ks * 32 + quad * 8;
        bh[nt] = *(const short8*)&wsh[SW(n, k0)];
        bl[nt] = *(const short8*)&wsl[SW(n, k0)];
      }
#pragma unroll
      for (int mt = 0; mt < 2; mt++)
#pragma unroll
        for (int nt = 0; nt < 2; nt++) {
          hacc[mt][nt] = __builtin_amdgcn_mfma_f32_16x16x32_bf16(
              xa_l[mt][ks], bh[nt], hacc[mt][nt], 0, 0, 0);
          hacc[mt][nt] = __builtin_amdgcn_mfma_f32_16x16x32_bf16(
              xa_h[mt][ks], bl[nt], hacc[mt][nt], 0, 0, 0);
          hacc[mt][nt] = __builtin_amdgcn_mfma_f32_16x16x32_bf16(
              xa_h[mt][ks], bh[nt], hacc[mt][nt], 0, 0, 0);
        }
    }
    // relu + write H tile as bf16 hi/lo
#pragma unroll
    for (int mt = 0; mt < 2; mt++)
#pragma unroll
      for (int nt = 0; nt < 2; nt++)
#pragma unroll
        for (int r = 0; r < 4; r++) {
          float v = fmaxf(hacc[mt][nt][r], 0.f);
          int m = wm * 32 + mt * 16 + quad * 4 + r;
          int c = wn * 32 + nt * 16 + l15;
          ushortT hi = bf16_rn(v);
          int id = SW(m, c);
          hsh[id] = hi;
          hsl[id] = bf16_rn(v - bf16f(hi));
        }
    __syncthreads();  // all GEMM1 wsh reads + H writes done
    // stage W2 chunk: rows n=0..63, k slice hcg*64..+64
    {
      const ushortT* g2h = w2t_hi + hcg * 64;
      const ushortT* g2l = w2t_lo + hcg * 64;
      for (int p = tid; p < 1024; p += 256) {
        int n = p >> 4, s = p & 15;
        int id = SW(n, s * 4);
        *(us4*)&wsh[id] = *(const us4*)&g2h[n * 2048 + s * 4];
        *(us4*)&wsl[id] = *(const us4*)&g2l[n * 2048 + s * 4];
      }
    }
    __syncthreads();  // W2 staged, H visible
    // GEMM2: acc += H @ W2chunk
#pragma unroll
    for (int ks = 0; ks < 2; ks++) {
      short8 ah[2], al[2], b2h[2], b2l[2];
#pragma unroll
      for (int mt = 0; mt < 2; mt++) {
        int m = wm * 32 + mt * 16 + l15;
        int k0 = ks * 32 + quad * 8;
        ah[mt] = *(const short8*)&hsh[SW(m, k0)];
        al[mt] = *(const short8*)&hsl[SW(m, k0)];
      }
#pragma unroll
      for (int nt = 0; nt < 2; nt++) {
        int n = wn * 32 + nt * 16 + l15;
        int k0 = ks * 32 + quad * 8;
        b2h[nt] = *(const short8*)&wsh[SW(n, k0)];
        b2l[nt] = *(const short8*)&wsl[SW(n, k0)];
      }
#pragma unroll
      for (int mt = 0; mt < 2; mt++)
#pragma unroll
        for (int nt = 0; nt < 2; nt++) {
          acc[mt][nt] = __builtin_amdgcn_mfma_f32_16x16x32_bf16(
              al[mt], b2h[nt], acc[mt][nt], 0, 0, 0);
          acc[mt][nt] = __builtin_amdgcn_mfma_f32_16x16x32_bf16(
              ah[mt], b2l[nt], acc[mt][nt], 0, 0, 0);
          acc[mt][nt] = __builtin_amdgcn_mfma_f32_16x16x32_bf16(
              ah[mt], b2h[nt], acc[mt][nt], 0, 0, 0);
        }
    }
  }
  // epilogue
#pragma unroll
  for (int mt = 0; mt < 2; mt++)
#pragma unroll
    for (int nt = 0; nt < 2; nt++)
#pragma unroll
      for (int r = 0; r < 4; r++) {
        int row = r0 + wm * 32 + mt * 16 + quad * 4 + r;
        int col = wn * 32 + nt * 16 + l15;
        out[(size_t)split * ((size_t)BL * 64) + (size_t)row * 64 + col] =
            acc[mt][nt][r];
      }
}

// ---------------- head: out[B,V,3] = x[:, -1] @ W_head + b_head ----------------
__global__ __launch_bounds__(256) void k_head(
    const float* __restrict__ x, const float* __restrict__ Wh,
    const float* __restrict__ bh, float* __restrict__ out)
{
  int id = blockIdx.x * 256 + threadIdx.x;  // < B*V = 1024
  int b = id >> 6, v = id & 63;
  const float* xr = x + (size_t)(b * LL + (SS - 1) * VVV + v) * 64;
  float a0 = bh[0], a1 = bh[1], a2 = bh[2];
  for (int e = 0; e < 64; e++) {
    float xv = xr[e];
    a0 += xv * Wh[e * 3 + 0];
    a1 += xv * Wh[e * 3 + 1];
    a2 += xv * Wh[e * 3 + 2];
  }
  out[id * 3 + 0] = a0;
  out[id * 3 + 1] = a1;
  out[id * 3 + 2] = a2;
}

extern "C" void kernel_launch(void* const* d_in, const int* in_sizes, int n_in,
                              void* d_out, int out_size, void* d_ws, size_t ws_size,
                              hipStream_t stream) {
  const float* features = (const float*)d_in[0];
  const int*   ovtag    = (const int*)d_in[1];
  const int*   poiid    = (const int*)d_in[2];
  const float* W_raw    = (const float*)d_in[3];
  const float* b_raw    = (const float*)d_in[4];
  const float* pos_tab  = (const float*)d_in[5];
  const float* type_tab = (const float*)d_in[6];
  const float* poi_tab  = (const float*)d_in[7];
  const float* ov_tab   = (const float*)d_in[8];
  const float* W_comb   = (const float*)d_in[9];
  const float* b_comb   = (const float*)d_in[10];
  const float* Wqkv     = (const float*)d_in[11];
  const float* bqkv     = (const float*)d_in[12];
  const float* Wo       = (const float*)d_in[13];
  const float* bo       = (const float*)d_in[14];
  const float* ln1_s    = (const float*)d_in[15];
  const float* ln1_b    = (const float*)d_in[16];
  const float* W1       = (const float*)d_in[17];
  const float* b1       = (const float*)d_in[18];
  const float* W2       = (const float*)d_in[19];
  const float* b2       = (const float*)d_in[20];
  const float* ln2_s    = (const float*)d_in[21];
  const float* ln2_b    = (const float*)d_in[22];
  const float* W_head   = (const float*)d_in[23];
  const float* b_head   = (const float*)d_in[24];
  float* out = (float*)d_out;
  float* ws  = (float*)d_ws;

  float* zm     = ws;                         // BL
  float* concat = zm + BL;                    // BL*80 floats (5.24 MB)
  float* x      = concat + (size_t)BL * 80;   // BL*64
  float* qkvb   = x + (size_t)BL * 64;        // BL*192
  float* obuf   = qkvb + (size_t)BL * 192;    // BL*64
  float* tmp    = obuf + (size_t)BL * 64;     // 4 * BL*64

  // bf16 hi/lo transposed weight copies alias the concat region (dead after comb GEMM)
  ushortT* w1t_hi = (ushortT*)concat;              // NL*2048*64
  ushortT* w1t_lo = w1t_hi + (size_t)NLAYER * PERL;
  ushortT* w2t_hi = w1t_lo + (size_t)NLAYER * PERL; // NL*64*2048
  ushortT* w2t_lo = w2t_hi + (size_t)NLAYER * PERL;

  k_embed<<<(BL * 80) / 256, 256, 0, stream>>>(features, ovtag, poiid, W_raw,
                                               b_raw, ov_tab, poi_tab, concat, zm);
  k_gemm<80><<<dim3(BL / 64, 1), 256, 0, stream>>>(concat, W_comb, b_comb, x,
                                                   64, 1, pos_tab, type_tab);
  // concat is dead now; build transposed bf16 weight copies in its place
  k_prep<<<(2 * NLAYER * PERL) / 256, 256, 0, stream>>>(W1, W2, w1t_hi, w1t_lo,
                                                        w2t_hi, w2t_lo);
  for (int l = 0; l < NLAYER; l++) {
    k_gemm<64><<<dim3(BL / 64, 3), 256, 0, stream>>>(
        x, Wqkv + (size_t)l * EE * 3 * EE, bqkv + l * 3 * EE, qkvb, 192, 0,
        nullptr, nullptr);
    k_attn<<<512, 256, 0, stream>>>(qkvb, zm, obuf);
    k_gemm<64><<<dim3(BL / 64, 1), 256, 0, stream>>>(
        obuf, Wo + (size_t)l * EE * EE, bo + l * EE, tmp, 64, 0, nullptr, nullptr);
    k_resln<<<BL / 4, 256, 0, stream>>>(x, tmp, 1, ln1_s + l * EE, ln1_b + l * EE);
    k_ffn<<<dim3(BL / 64, 4), 256, 0, stream>>>(
        x, w1t_hi + (size_t)l * PERL, w1t_lo + (size_t)l * PERL,
        w2t_hi + (size_t)l * PERL, w2t_lo + (size_t)l * PERL,
        b1 + l * DFF_, b2 + l * EE, tmp);
    k_resln<<<BL / 4, 256, 0, stream>>>(x, tmp, 4, ln2_s + l * EE, ln2_b + l * EE);
  }
  k_head<<<4, 256, 0, stream>>>(x, W_head, b_head, out);
}

// Round 3
// 534.187 us; speedup vs baseline: 1.9149x; 1.3052x over previous
//
#include <hip/hip_runtime.h>
#include <math.h>

#define BB 16
#define SS 16
#define VVV 64
#define EE 64
#define HHH 8
#define NLAYER 4
#define DFF_ 2048
#define LL 1024   /* S*V */
#define BL 16384  /* B*L */
#define PERL 131072  /* 64*2048 elems per layer of W1 (and W2) */

typedef __attribute__((ext_vector_type(8))) _Float16 half8;
typedef __attribute__((ext_vector_type(4))) _Float16 half4v;
typedef __attribute__((ext_vector_type(4))) float f32x4;

// XOR-swizzled index into a [64][64] fp16 LDS tile (16B granules, measured 0 conflicts)
#define SW(m, k) (((m) << 6) + ((((k) >> 3) ^ ((m) & 7)) << 3) + ((k) & 7))

// ---------------- embed: concat = [feat@W_raw+b, ov_emb, poi_emb]; zero mask ----------------
__global__ __launch_bounds__(256) void k_embed(
    const float* __restrict__ features, const int* __restrict__ ovtag,
    const int* __restrict__ poiid, const float* __restrict__ W_raw,
    const float* __restrict__ b_raw, const float* __restrict__ ov_tab,
    const float* __restrict__ poi_tab, float* __restrict__ concat,
    float* __restrict__ zm)
{
  int idx = blockIdx.x * 256 + threadIdx.x;       // < BL*80
  int row = idx / 80;
  int c   = idx - row * 80;
  float f0 = features[row * 3 + 0];
  float f1 = features[row * 3 + 1];
  float f2 = features[row * 3 + 2];
  float out;
  if (c < 64) {
    out = b_raw[c] + f0 * W_raw[c] + f1 * W_raw[64 + c] + f2 * W_raw[128 + c];
  } else if (c < 72) {
    int t = ovtag[row]; int j = c - 64;
    out = (t <= 0) ? 0.f : ov_tab[t * 8 + j];     // padding_idx=0 -> zeros
  } else {
    int t = poiid[row]; int j = c - 72;
    out = (t <= 0) ? 0.f : poi_tab[t * 8 + j];    // padding_idx=0 -> zeros
  }
  concat[idx] = out;
  if (c == 0) zm[row] = ((f0 + f1 + f2) == 0.f) ? 1.f : 0.f;
}

// ---------------- coalesced transpose + fp32->fp16: dst[c][r] = src[r][c] ----------------
__global__ __launch_bounds__(256) void k_tr(
    const float* __restrict__ src, _Float16* __restrict__ dst,
    int R, int C, long lsrc, long ldst)
{
  __shared__ float t[64][65];
  const float* s = src + (size_t)blockIdx.z * lsrc;
  _Float16* d = dst + (size_t)blockIdx.z * ldst;
  int c0 = blockIdx.x * 64, r0 = blockIdx.y * 64;
  int cc = threadIdx.x & 63, rr = threadIdx.x >> 6;
#pragma unroll
  for (int i = 0; i < 16; i++) {
    int r = i * 4 + rr;
    if (r0 + r < R && c0 + cc < C)
      t[r][cc] = s[(size_t)(r0 + r) * C + c0 + cc];
  }
  __syncthreads();
#pragma unroll
  for (int i = 0; i < 16; i++) {
    int c = i * 4 + rr;
    if (c0 + c < C && r0 + cc < R)
      d[(size_t)(c0 + c) * R + r0 + cc] = (_Float16)t[cc][c];
  }
}

// ---------------- fp16 MFMA GEMM: C[M,N] = A[M,AK]@Bt[N,AK]^T + bias (+pos/type) -----------
// Bt is pre-transposed fp16 [N][AK]. KK = AK rounded up to multiple of 32.
template <int KK>
__global__ __launch_bounds__(256) void k_gemm16(
    const float* __restrict__ A, const _Float16* __restrict__ Bt, int AK,
    const float* __restrict__ bias, float* __restrict__ C, int N, int addpos,
    const float* __restrict__ pos_tab, const float* __restrict__ type_tab)
{
  constexpr int KP = KK + 8;     // padded row stride (halves); rows 16B-aligned
  constexpr int S4 = KK / 4;
  __shared__ _Float16 As[64 * KP];
  __shared__ _Float16 Bs[64 * KP];
  int tid = threadIdx.x;
  int m0 = blockIdx.x * 64, n0 = blockIdx.y * 64;
  int wave = tid >> 6, lane = tid & 63, quad = lane >> 4, l15 = lane & 15;
  int wm = wave >> 1, wn = wave & 1;
  for (int p = tid; p < 64 * S4; p += 256) {
    int r = p / S4, s = p - r * S4; int c = s * 4;
    half4v h;
    if (c < AK) {
      float4 f = *(const float4*)&A[(size_t)(m0 + r) * AK + c];
      h = (half4v){(_Float16)f.x, (_Float16)f.y, (_Float16)f.z, (_Float16)f.w};
    } else h = (half4v){0, 0, 0, 0};
    *(half4v*)&As[r * KP + c] = h;
  }
  for (int p = tid; p < 64 * S4; p += 256) {
    int r = p / S4, s = p - r * S4; int c = s * 4;
    half4v h;
    if (c < AK) h = *(const half4v*)&Bt[(size_t)(n0 + r) * AK + c];
    else h = (half4v){0, 0, 0, 0};
    *(half4v*)&Bs[r * KP + c] = h;
  }
  __syncthreads();
  f32x4 acc[2][2];
#pragma unroll
  for (int mt = 0; mt < 2; mt++)
#pragma unroll
    for (int nt = 0; nt < 2; nt++) {
      float bv = bias[n0 + wn * 32 + nt * 16 + l15];
      acc[mt][nt] = (f32x4){bv, bv, bv, bv};
    }
#pragma unroll
  for (int ks = 0; ks < KK / 32; ks++) {
    half8 af[2], bf[2];
#pragma unroll
    for (int mt = 0; mt < 2; mt++)
      af[mt] = *(const half8*)&As[(wm * 32 + mt * 16 + l15) * KP + ks * 32 + quad * 8];
#pragma unroll
    for (int nt = 0; nt < 2; nt++)
      bf[nt] = *(const half8*)&Bs[(wn * 32 + nt * 16 + l15) * KP + ks * 32 + quad * 8];
#pragma unroll
    for (int mt = 0; mt < 2; mt++)
#pragma unroll
      for (int nt = 0; nt < 2; nt++)
        acc[mt][nt] = __builtin_amdgcn_mfma_f32_16x16x32_f16(af[mt], bf[nt],
                                                             acc[mt][nt], 0, 0, 0);
  }
#pragma unroll
  for (int mt = 0; mt < 2; mt++)
#pragma unroll
    for (int nt = 0; nt < 2; nt++)
#pragma unroll
      for (int r = 0; r < 4; r++) {
        int row = m0 + wm * 32 + mt * 16 + quad * 4 + r;
        int col = n0 + wn * 32 + nt * 16 + l15;
        float v = acc[mt][nt][r];
        if (addpos) {
          int l = row & (LL - 1);
          v += pos_tab[(l >> 6) * 64 + col] + type_tab[(l & 63) * 64 + col];
        }
        C[(size_t)row * N + col] = v;
      }
}

// ---------------- fused FFN fp16 MFMA: out_part[split] = relu(x@W1[:,rng]+b1)@W2[rng,:] ----
// w1t fp16 [2048][64] (k-contig), w2t fp16 [64][2048]. GEMM1 computed transposed so the
// H C-layout packs into b64 LDS writes. split in {0,1}: hidden range split*1024..+1024.
__global__ __launch_bounds__(256) void k_ffn16(
    const float* __restrict__ x, const _Float16* __restrict__ w1t,
    const _Float16* __restrict__ w2t, const float* __restrict__ b1,
    const float* __restrict__ b2, float* __restrict__ out)
{
  __shared__ _Float16 xs[4096];
  __shared__ _Float16 ws1[4096];
  __shared__ _Float16 ws2[4096];
  __shared__ _Float16 hs[4096];
  __shared__ float bs1[1024];
  int tid = threadIdx.x;
  int r0 = blockIdx.x * 64;
  int split = blockIdx.y;                    // 0..1
  int wave = tid >> 6, lane = tid & 63;
  int quad = lane >> 4, l15 = lane & 15;
  int wa = wave >> 1, wb = wave & 1;

  // stage x tile (fp32 -> fp16, swizzled)
  const float* xt = x + (size_t)r0 * 64;
  for (int p = tid; p < 1024; p += 256) {
    int m = p >> 4, c = (p & 15) << 2;
    float4 f = *(const float4*)&xt[m * 64 + c];
    half4v h = (half4v){(_Float16)f.x, (_Float16)f.y, (_Float16)f.z, (_Float16)f.w};
    *(half4v*)&xs[SW(m, c)] = h;
  }
  for (int p = tid; p < 1024; p += 256) bs1[p] = b1[split * 1024 + p];
  __syncthreads();

  // hoist x B-frags for GEMM1^T (constant across all 16 chunks)
  half8 xb[2][2];
#pragma unroll
  for (int mt = 0; mt < 2; mt++)
#pragma unroll
    for (int ks = 0; ks < 2; ks++)
      xb[mt][ks] = *(const half8*)&xs[SW(wb * 32 + mt * 16 + l15, ks * 32 + quad * 8)];

  f32x4 acc[2][2];   // GEMM2 acc: m = wa*32+mt*16+quad*4+r, n = wb*32+nt*16+l15
#pragma unroll
  for (int mt = 0; mt < 2; mt++)
#pragma unroll
    for (int nt = 0; nt < 2; nt++) {
      float bv = (split == 0) ? b2[wb * 32 + nt * 16 + l15] : 0.f;
      acc[mt][nt] = (f32x4){bv, bv, bv, bv};
    }

  for (int i = 0; i < 16; i++) {
    int hc = split * 16 + i;   // 64-wide hidden chunk index
    __syncthreads();           // prev iter's GEMM reads done
    {  // stage W1 chunk rows [hc*64,+64) of w1t (contiguous) and W2 col-slice
      const _Float16* g1 = w1t + (size_t)hc * 4096;
      const _Float16* g2 = w2t + hc * 64;
      for (int p = tid; p < 1024; p += 256) {
        int n = p >> 4, s = (p & 15) << 2;
        *(half4v*)&ws1[SW(n, s)] = *(const half4v*)&g1[n * 64 + s];
        *(half4v*)&ws2[SW(n, s)] = *(const half4v*)&g2[(size_t)n * 2048 + s];
      }
    }
    __syncthreads();
    // GEMM1^T: Ht[n][m] = sum_k W1c[k][n] x[m][k]; A = w1t rows, B = xs rows
    f32x4 hacc[2][2];  // [nt][mt]
#pragma unroll
    for (int nt = 0; nt < 2; nt++)
#pragma unroll
      for (int mt = 0; mt < 2; mt++) hacc[nt][mt] = (f32x4){0.f, 0.f, 0.f, 0.f};
#pragma unroll
    for (int ks = 0; ks < 2; ks++) {
      half8 a1[2];
#pragma unroll
      for (int nt = 0; nt < 2; nt++)
        a1[nt] = *(const half8*)&ws1[SW(wa * 32 + nt * 16 + l15, ks * 32 + quad * 8)];
#pragma unroll
      for (int nt = 0; nt < 2; nt++)
#pragma unroll
        for (int mt = 0; mt < 2; mt++)
          hacc[nt][mt] = __builtin_amdgcn_mfma_f32_16x16x32_f16(a1[nt], xb[mt][ks],
                                                                hacc[nt][mt], 0, 0, 0);
    }
    // bias + relu + fp16 pack; 4 consecutive hidden per quad -> b64 LDS writes
#pragma unroll
    for (int nt = 0; nt < 2; nt++) {
      int nloc = wa * 32 + nt * 16 + quad * 4;
      float4 bb = *(const float4*)&bs1[i * 64 + nloc];
#pragma unroll
      for (int mt = 0; mt < 2; mt++) {
        f32x4 h = hacc[nt][mt];
        half4v hp = (half4v){
            (_Float16)fmaxf(h[0] + bb.x, 0.f), (_Float16)fmaxf(h[1] + bb.y, 0.f),
            (_Float16)fmaxf(h[2] + bb.z, 0.f), (_Float16)fmaxf(h[3] + bb.w, 0.f)};
        *(half4v*)&hs[SW(wb * 32 + mt * 16 + l15, nloc)] = hp;
      }
    }
    __syncthreads();
    // GEMM2: acc += H[m][k] @ W2c[k][n]; A = hs rows, B = ws2 rows
#pragma unroll
    for (int ks = 0; ks < 2; ks++) {
      half8 a2[2], b2f[2];
#pragma unroll
      for (int mt = 0; mt < 2; mt++)
        a2[mt] = *(const half8*)&hs[SW(wa * 32 + mt * 16 + l15, ks * 32 + quad * 8)];
#pragma unroll
      for (int nt = 0; nt < 2; nt++)
        b2f[nt] = *(const half8*)&ws2[SW(wb * 32 + nt * 16 + l15, ks * 32 + quad * 8)];
#pragma unroll
      for (int mt = 0; mt < 2; mt++)
#pragma unroll
        for (int nt = 0; nt < 2; nt++)
          acc[mt][nt] = __builtin_amdgcn_mfma_f32_16x16x32_f16(a2[mt], b2f[nt],
                                                               acc[mt][nt], 0, 0, 0);
    }
  }
#pragma unroll
  for (int mt = 0; mt < 2; mt++)
#pragma unroll
    for (int nt = 0; nt < 2; nt++)
#pragma unroll
      for (int r = 0; r < 4; r++) {
        int row = r0 + wa * 32 + mt * 16 + quad * 4 + r;
        int col = wb * 32 + nt * 16 + l15;
        out[(size_t)split * ((size_t)BL * 64) + (size_t)row * 64 + col] =
            acc[mt][nt][r];
      }
}

// ---------------- attention: block = (b, h, 256 q-rows); masked online softmax ----------------
__global__ __launch_bounds__(256) void k_attn(
    const float* __restrict__ qkv, const float* __restrict__ zm,
    float* __restrict__ obuf)
{
  __shared__ float KsT[8 * 1024];
  __shared__ float VsT[8 * 1024];
  int blk = blockIdx.x;
  int qb = blk & 3, h = (blk >> 2) & 7, b = blk >> 5;
  const float* base = qkv + (size_t)b * LL * 192;
  for (int p = threadIdx.x; p < 8192; p += 256) {
    int k = p >> 3, d = p & 7;
    KsT[d * 1024 + k] = base[(size_t)k * 192 + 64 + h * 8 + d];
    VsT[d * 1024 + k] = base[(size_t)k * 192 + 128 + h * 8 + d];
  }
  __syncthreads();
  int qrow = qb * 256 + threadIdx.x;
  int tq = qrow >> 6, vq = qrow & 63;
  const float* zmb = zm + b * LL;
  float q[8];
#pragma unroll
  for (int d = 0; d < 8; d++) q[d] = base[(size_t)qrow * 192 + h * 8 + d];
  const float scale = 0.3535533905932738f;
  float m = -INFINITY, lsum = 0.f;
  float acc[8] = {0.f, 0.f, 0.f, 0.f, 0.f, 0.f, 0.f, 0.f};
  bool zmq = (zmb[qrow] != 0.f);

  auto attend = [&](int k) {
    if (zmb[k] != 0.f) return;
    float s = 0.f;
#pragma unroll
    for (int d = 0; d < 8; d++) s += q[d] * KsT[d * 1024 + k];
    s *= scale;
    if (s <= m) {
      float p = __expf(s - m);
      lsum += p;
#pragma unroll
      for (int d = 0; d < 8; d++) acc[d] += p * VsT[d * 1024 + k];
    } else {
      float r = __expf(m - s);
      lsum = lsum * r + 1.f;
#pragma unroll
      for (int d = 0; d < 8; d++) acc[d] = acc[d] * r + VsT[d * 1024 + k];
      m = s;
    }
  };

  if (!zmq) {
    for (int vv = 0; vv < 64; vv++) attend(tq * 64 + vv);
    for (int tt = 0; tt < 16; tt++) {
      if (tt == tq) continue;
      attend(tt * 64 + vq);
    }
  }
  float inv = 1.f / lsum;
  float* orow = obuf + (size_t)(b * LL + qrow) * 64 + h * 8;
#pragma unroll
  for (int d = 0; d < 8; d++) orow[d] = acc[d] * inv;
}

// ---------------- residual + LayerNorm (wave per row), in-place on x ----------------
__global__ __launch_bounds__(256) void k_resln(
    float* __restrict__ x, const float* __restrict__ tmp, int nparts,
    const float* __restrict__ sc, const float* __restrict__ bs)
{
  int lane = threadIdx.x & 63;
  int row = blockIdx.x * 4 + (threadIdx.x >> 6);
  size_t off = (size_t)row * 64 + lane;
  float val = x[off];
  for (int p = 0; p < nparts; p++) val += tmp[(size_t)p * ((size_t)BL * 64) + off];
  float sum = val;
#pragma unroll
  for (int o = 32; o > 0; o >>= 1) sum += __shfl_xor(sum, o);
  float mean = sum * (1.f / 64.f);
  float d = val - mean;
  float sq = d * d;
#pragma unroll
  for (int o = 32; o > 0; o >>= 1) sq += __shfl_xor(sq, o);
  float var = sq * (1.f / 64.f);
  x[off] = d * rsqrtf(var + 1e-5f) * sc[lane] + bs[lane];
}

// ---------------- head: out[B,V,3] = x[:, -1] @ W_head + b_head ----------------
__global__ __launch_bounds__(256) void k_head(
    const float* __restrict__ x, const float* __restrict__ Wh,
    const float* __restrict__ bh, float* __restrict__ out)
{
  int id = blockIdx.x * 256 + threadIdx.x;  // < B*V = 1024
  int b = id >> 6, v = id & 63;
  const float* xr = x + (size_t)(b * LL + (SS - 1) * VVV + v) * 64;
  float a0 = bh[0], a1 = bh[1], a2 = bh[2];
  for (int e = 0; e < 64; e++) {
    float xv = xr[e];
    a0 += xv * Wh[e * 3 + 0];
    a1 += xv * Wh[e * 3 + 1];
    a2 += xv * Wh[e * 3 + 2];
  }
  out[id * 3 + 0] = a0;
  out[id * 3 + 1] = a1;
  out[id * 3 + 2] = a2;
}

extern "C" void kernel_launch(void* const* d_in, const int* in_sizes, int n_in,
                              void* d_out, int out_size, void* d_ws, size_t ws_size,
                              hipStream_t stream) {
  const float* features = (const float*)d_in[0];
  const int*   ovtag    = (const int*)d_in[1];
  const int*   poiid    = (const int*)d_in[2];
  const float* W_raw    = (const float*)d_in[3];
  const float* b_raw    = (const float*)d_in[4];
  const float* pos_tab  = (const float*)d_in[5];
  const float* type_tab = (const float*)d_in[6];
  const float* poi_tab  = (const float*)d_in[7];
  const float* ov_tab   = (const float*)d_in[8];
  const float* W_comb   = (const float*)d_in[9];
  const float* b_comb   = (const float*)d_in[10];
  const float* Wqkv     = (const float*)d_in[11];
  const float* bqkv     = (const float*)d_in[12];
  const float* Wo       = (const float*)d_in[13];
  const float* bo       = (const float*)d_in[14];
  const float* ln1_s    = (const float*)d_in[15];
  const float* ln1_b    = (const float*)d_in[16];
  const float* W1       = (const float*)d_in[17];
  const float* b1       = (const float*)d_in[18];
  const float* W2       = (const float*)d_in[19];
  const float* b2       = (const float*)d_in[20];
  const float* ln2_s    = (const float*)d_in[21];
  const float* ln2_b    = (const float*)d_in[22];
  const float* W_head   = (const float*)d_in[23];
  const float* b_head   = (const float*)d_in[24];
  float* out = (float*)d_out;
  float* ws  = (float*)d_ws;

  float* zm     = ws;                          // BL
  float* concat = zm + BL;                     // BL*80 (dead after comb gemm)
  float* x      = concat + (size_t)BL * 80;    // BL*64
  float* qkvb   = x + (size_t)BL * 64;         // BL*192
  float* obuf   = qkvb + (size_t)BL * 192;     // BL*64
  float* tmp    = obuf + (size_t)BL * 64;      // 2 * BL*64
  float* wcombt_f = tmp + 2 * (size_t)BL * 64; // 2560 floats (5120 halves)

  _Float16* wcombt = (_Float16*)wcombt_f;            // [64][80]
  _Float16* w1t    = (_Float16*)concat;              // [NL][2048][64]
  _Float16* w2t    = w1t + (size_t)NLAYER * PERL;    // [NL][64][2048]
  _Float16* wqkvt  = w2t + (size_t)NLAYER * PERL;    // [NL][192][64]
  _Float16* wot    = wqkvt + (size_t)NLAYER * 192 * 64;  // [NL][64][64]

  k_embed<<<(BL * 80) / 256, 256, 0, stream>>>(features, ovtag, poiid, W_raw,
                                               b_raw, ov_tab, poi_tab, concat, zm);
  k_tr<<<dim3(1, 2, 1), 256, 0, stream>>>(W_comb, wcombt, 80, 64, 0, 0);
  k_gemm16<96><<<dim3(BL / 64, 1), 256, 0, stream>>>(
      concat, wcombt, 80, b_comb, x, 64, 1, pos_tab, type_tab);
  // concat dead; build transposed fp16 weights in its place
  k_tr<<<dim3(32, 1, 4), 256, 0, stream>>>(W1, w1t, 64, 2048, PERL, PERL);
  k_tr<<<dim3(1, 32, 4), 256, 0, stream>>>(W2, w2t, 2048, 64, PERL, PERL);
  k_tr<<<dim3(3, 1, 4), 256, 0, stream>>>(Wqkv, wqkvt, 64, 192, 64 * 192, 64 * 192);
  k_tr<<<dim3(1, 1, 4), 256, 0, stream>>>(Wo, wot, 64, 64, 64 * 64, 64 * 64);

  for (int l = 0; l < NLAYER; l++) {
    k_gemm16<64><<<dim3(BL / 64, 3), 256, 0, stream>>>(
        x, wqkvt + (size_t)l * 192 * 64, 64, bqkv + l * 192, qkvb, 192, 0,
        nullptr, nullptr);
    k_attn<<<512, 256, 0, stream>>>(qkvb, zm, obuf);
    k_gemm16<64><<<dim3(BL / 64, 1), 256, 0, stream>>>(
        obuf, wot + (size_t)l * 64 * 64, 64, bo + l * EE, tmp, 64, 0,
        nullptr, nullptr);
    k_resln<<<BL / 4, 256, 0, stream>>>(x, tmp, 1, ln1_s + l * EE, ln1_b + l * EE);
    k_ffn16<<<dim3(BL / 64, 2), 256, 0, stream>>>(
        x, w1t + (size_t)l * PERL, w2t + (size_t)l * PERL,
        b1 + l * DFF_, b2 + l * EE, tmp);
    k_resln<<<BL / 4, 256, 0, stream>>>(x, tmp, 2, ln2_s + l * EE, ln2_b + l * EE);
  }
  k_head<<<4, 256, 0, stream>>>(x, W_head, b_head, out);
}